// Round 2
// baseline (27.157 us; speedup 1.0000x reference)
//
#include <hip/hip_runtime.h>

#define KNBR 32
#define G 8
#define OBS 16
#define KP 4          // neighbors per thread
#define TPQ 8         // threads per query
#define BLOCK 256

// repack points (N,3) -> float4 (N) so the main kernel's random gather is
// one 16B-aligned dwordx4 (single cache line) instead of 3 scattered dwords.
__global__ __launch_bounds__(256) void repack_kernel(
    const float* __restrict__ pts, float4* __restrict__ out, int N)
{
    const int i = blockIdx.x * 256 + threadIdx.x;
    if (i < N) {
        out[i] = make_float4(pts[3*i], pts[3*i+1], pts[3*i+2], 0.0f);
    }
}

template<int PACKED>
__global__ __launch_bounds__(BLOCK, 8) void gib_kernel(
    const float* __restrict__ points,      // raw (N,3) when !PACKED
    const float4* __restrict__ pts4,       // packed (N) when PACKED
    const float* __restrict__ q_coords,
    const int*   __restrict__ sidx,
    const float* __restrict__ cy_radius,
    const float* __restrict__ disk_radius,
    const float* __restrict__ disk_width,
    const float* __restrict__ cone_radius,
    const float* __restrict__ cone_inc,
    const float* __restrict__ ellip_radii,
    const float* __restrict__ lambdas,
    float* __restrict__ out,
    int M)
{
    // per-g params packed for ds_read_b128 pair:
    // [g][0..7] = ccy, inc, ccn, da, db, e_xy, e_xx, e_zz
    __shared__ float s_par[G * 8];
    __shared__ float s_lam[4 * G * OBS];   // (32,16) row-major

    const float NL2E = -0.5f * 1.44269504088896340736f;
    const float EPS  = 1e-8f;

    const int t = threadIdx.x;
    if (t < G) {
        float r;
        r = cy_radius[t];        s_par[t*8 + 0] = NL2E / (r*r + EPS);
        s_par[t*8 + 1] = cone_inc[t];
        r = cone_radius[t];      s_par[t*8 + 2] = NL2E / (r*r + EPS);
        r = disk_radius[t];      s_par[t*8 + 3] = NL2E / (r*r + EPS);
        r = disk_width[t];       s_par[t*8 + 4] = NL2E / (r*r + EPS);
        float ra = ellip_radii[3*t+0];
        float rb = ellip_radii[3*t+1];
        float rc = ellip_radii[3*t+2];
        float ea = NL2E / (ra*ra + EPS);
        float eb = NL2E / (rb*rb + EPS);
        float ec = NL2E / (rc*rc + EPS);
        // x2*ea + y2*eb + z2*ec == xy2*eb + x2*(ea-eb) + z2*ec
        s_par[t*8 + 5] = eb;        // coeff of xy2
        s_par[t*8 + 6] = ea - eb;   // coeff of x2
        s_par[t*8 + 7] = ec;        // coeff of z2
    }
    s_lam[t]       = lambdas[t];
    s_lam[t + 256] = lambdas[t + 256];
    __syncthreads();

    const int gid = blockIdx.x * BLOCK + t;
    const int m   = gid >> 3;       // query index
    const int sub = t & 7;          // which eighth of K / which column pair
    if (m >= M) return;

    const float qx = q_coords[3*m + 0];
    const float qy = q_coords[3*m + 1];
    const float qz = q_coords[3*m + 2];

    // 4 neighbor indices: one int4 (8 lanes cover 128B contiguous per query)
    const int4 iv = *(const int4*)(sidx + (size_t)m * KNBR + sub * KP);
    const int id[KP] = {iv.x, iv.y, iv.z, iv.w};

    // gather the 4 points first (independent loads batch in flight)
    float px[KP], py[KP], pz[KP];
    if (PACKED) {
        #pragma unroll
        for (int j = 0; j < KP; j++) {
            float4 p = pts4[id[j]];
            px[j] = p.x; py[j] = p.y; pz[j] = p.z;
        }
    } else {
        #pragma unroll
        for (int j = 0; j < KP; j++) {
            const float* p = points + 3*(size_t)id[j];
            px[j] = p[0]; py[j] = p[1]; pz[j] = p[2];
        }
    }

    float x2[KP], z2[KP], xy2[KP], rxy[KP], zz[KP];
    const float INF = __builtin_inff();
    #pragma unroll
    for (int j = 0; j < KP; j++) {
        float rx = px[j]-qx, ry = py[j]-qy, rz = pz[j]-qz;
        float a = rx*rx, b = ry*ry, c = rz*rz;
        bool act = (a + b + c <= 1.0f);      // REACH^2 = 1
        // masked neighbor: drive exp2 args to -inf -> weight exactly 0.
        // x2 must be 0 (not INF): its coeff (ea-eb) can be positive -> NaN risk;
        // xy2=INF (negative coeff) already forces the ellip arg to -inf.
        x2[j]  = act ? a : 0.0f;
        z2[j]  = act ? c : INF;
        xy2[j] = act ? (a+b) : INF;
        rxy[j] = act ? __builtin_amdgcn_sqrtf(a+b+EPS) : INF;
        zz[j]  = rz;
    }

    float o0 = 0.f, o1 = 0.f;
    const float2* lamp = (const float2*)s_lam + sub;   // row stride = 8 float2

    #pragma unroll
    for (int g = 0; g < G; g++) {
        const float4 pA = *(const float4*)(s_par + g*8);     // ccy,inc,ccn,da
        const float4 pB = *(const float4*)(s_par + g*8 + 4); // db,exy,exx,ezz
        float a0=0.f, a1=0.f, a2=0.f, a3=0.f;
        #pragma unroll
        for (int j = 0; j < KP; j++) {
            // cylinder
            a0 += __builtin_amdgcn_exp2f(xy2[j] * pA.x);
            // cone
            float d = __builtin_fmaf(-pA.y, zz[j], rxy[j]);
            a1 += __builtin_amdgcn_exp2f(d*d * pA.z);
            // disk
            a2 += __builtin_amdgcn_exp2f(__builtin_fmaf(xy2[j], pA.w, z2[j]*pB.x));
            // ellipsoid
            a3 += __builtin_amdgcn_exp2f(__builtin_fmaf(xy2[j], pB.y,
                          __builtin_fmaf(x2[j], pB.z, z2[j]*pB.w)));
        }
        // allreduce the 4 kind-partials across the 8 lanes of this query
        a0 += __shfl_xor(a0,1); a0 += __shfl_xor(a0,2); a0 += __shfl_xor(a0,4);
        a1 += __shfl_xor(a1,1); a1 += __shfl_xor(a1,2); a1 += __shfl_xor(a1,4);
        a2 += __shfl_xor(a2,1); a2 += __shfl_xor(a2,2); a2 += __shfl_xor(a2,4);
        a3 += __shfl_xor(a3,1); a3 += __shfl_xor(a3,2); a3 += __shfl_xor(a3,4);
        // fold lambda for this thread's 2 output columns immediately
        float2 l;
        l = lamp[(      g)*8]; o0 = __builtin_fmaf(a0,l.x,o0); o1 = __builtin_fmaf(a0,l.y,o1);
        l = lamp[(G   + g)*8]; o0 = __builtin_fmaf(a1,l.x,o0); o1 = __builtin_fmaf(a1,l.y,o1);
        l = lamp[(2*G + g)*8]; o0 = __builtin_fmaf(a2,l.x,o0); o1 = __builtin_fmaf(a2,l.y,o1);
        l = lamp[(3*G + g)*8]; o0 = __builtin_fmaf(a3,l.x,o0); o1 = __builtin_fmaf(a3,l.y,o1);
    }

    const float s = 1.0f / (float)KNBR;
    *(float2*)(out + (size_t)m * OBS + sub*2) = make_float2(o0*s, o1*s);
}

extern "C" void kernel_launch(void* const* d_in, const int* in_sizes, int n_in,
                              void* d_out, int out_size, void* d_ws, size_t ws_size,
                              hipStream_t stream) {
    const float* points      = (const float*)d_in[0];
    const float* q_coords    = (const float*)d_in[1];
    const int*   sidx        = (const int*)  d_in[2];
    const float* cy_radius   = (const float*)d_in[3];
    const float* disk_radius = (const float*)d_in[4];
    const float* disk_width  = (const float*)d_in[5];
    const float* cone_radius = (const float*)d_in[6];
    const float* cone_inc    = (const float*)d_in[7];
    const float* ellip_radii = (const float*)d_in[8];
    const float* lambdas     = (const float*)d_in[9];
    float* out = (float*)d_out;

    const int N = in_sizes[0] / 3;
    const int M = in_sizes[1] / 3;
    const int grid = (M * TPQ + BLOCK - 1) / BLOCK;

    if (ws_size >= (size_t)N * 16) {
        float4* pts4 = (float4*)d_ws;
        repack_kernel<<<(N + 255) / 256, 256, 0, stream>>>(points, pts4, N);
        gib_kernel<1><<<grid, BLOCK, 0, stream>>>(points, pts4, q_coords, sidx,
                                                  cy_radius, disk_radius, disk_width,
                                                  cone_radius, cone_inc, ellip_radii,
                                                  lambdas, out, M);
    } else {
        gib_kernel<0><<<grid, BLOCK, 0, stream>>>(points, nullptr, q_coords, sidx,
                                                  cy_radius, disk_radius, disk_width,
                                                  cone_radius, cone_inc, ellip_radii,
                                                  lambdas, out, M);
    }
}

// Round 3
// 21.177 us; speedup vs baseline: 1.2823x; 1.2823x over previous
//
#include <hip/hip_runtime.h>

#define KNBR 32
#define G 8
#define OBS 16
#define KP 4          // neighbors per thread
#define TPQ 8         // threads per query
#define BLOCK 256

// float4 with relaxed alignment: lets us issue ONE global_load_dwordx4 at a
// 4B-aligned address (CDNA supports unaligned global vector loads) covering
// the 12B float3, instead of 3 scattered global_load_dword.
typedef float f4u __attribute__((ext_vector_type(4), aligned(4)));

__global__ __launch_bounds__(BLOCK, 8) void gib_kernel(
    const float* __restrict__ points,
    const float* __restrict__ q_coords,
    const int*   __restrict__ sidx,
    const float* __restrict__ cy_radius,
    const float* __restrict__ disk_radius,
    const float* __restrict__ disk_width,
    const float* __restrict__ cone_radius,
    const float* __restrict__ cone_inc,
    const float* __restrict__ ellip_radii,
    const float* __restrict__ lambdas,
    float* __restrict__ out,
    int M, int N)
{
    // per-g params packed for ds_read_b128 pair:
    // [g][0..7] = ccy, inc, ccn, da, db, e_xy, e_xx, e_zz
    __shared__ float s_par[G * 8];
    __shared__ float s_lam[4 * G * OBS];   // (32,16) row-major

    const float NL2E = -0.5f * 1.44269504088896340736f;
    const float EPS  = 1e-8f;

    const int t = threadIdx.x;
    if (t < G) {
        float r;
        r = cy_radius[t];        s_par[t*8 + 0] = NL2E / (r*r + EPS);
        s_par[t*8 + 1] = cone_inc[t];
        r = cone_radius[t];      s_par[t*8 + 2] = NL2E / (r*r + EPS);
        r = disk_radius[t];      s_par[t*8 + 3] = NL2E / (r*r + EPS);
        r = disk_width[t];       s_par[t*8 + 4] = NL2E / (r*r + EPS);
        float ra = ellip_radii[3*t+0];
        float rb = ellip_radii[3*t+1];
        float rc = ellip_radii[3*t+2];
        float ea = NL2E / (ra*ra + EPS);
        float eb = NL2E / (rb*rb + EPS);
        float ec = NL2E / (rc*rc + EPS);
        // x2*ea + y2*eb + z2*ec == xy2*eb + x2*(ea-eb) + z2*ec
        s_par[t*8 + 5] = eb;        // coeff of xy2
        s_par[t*8 + 6] = ea - eb;   // coeff of x2
        s_par[t*8 + 7] = ec;        // coeff of z2
    }
    s_lam[t]       = lambdas[t];
    s_lam[t + 256] = lambdas[t + 256];
    __syncthreads();

    const int gid = blockIdx.x * BLOCK + t;
    const int m   = gid >> 3;       // query index
    const int sub = t & 7;          // which eighth of K / which column pair
    if (m >= M) return;

    // 4 neighbor indices: one int4 (8 lanes cover 128B contiguous per query)
    const int4 iv = *(const int4*)(sidx + (size_t)m * KNBR + sub * KP);
    const int id[KP] = {iv.x, iv.y, iv.z, iv.w};

    const float qx = q_coords[3*m + 0];
    const float qy = q_coords[3*m + 1];
    const float qz = q_coords[3*m + 2];

    // gather: ONE dwordx4 per point (4B-aligned), clamped so the 16B window
    // never passes the end of the (N,3) buffer. shift is 1 only for id==N-1.
    float px[KP], py[KP], pz[KP];
    const int maxoff = 3 * N - 4;
    #pragma unroll
    for (int j = 0; j < KP; j++) {
        int off  = 3 * id[j];
        int offc = off > maxoff ? maxoff : off;
        f4u p = *(const f4u*)(points + offc);
        bool sh = (off != offc);
        px[j] = sh ? p.y : p.x;
        py[j] = sh ? p.z : p.y;
        pz[j] = sh ? p.w : p.z;
    }

    float x2[KP], z2[KP], xy2[KP], rxy[KP], zz[KP];
    const float INF = __builtin_inff();
    #pragma unroll
    for (int j = 0; j < KP; j++) {
        float rx = px[j]-qx, ry = py[j]-qy, rz = pz[j]-qz;
        float a = rx*rx, b = ry*ry, c = rz*rz;
        bool act = (a + b + c <= 1.0f);      // REACH^2 = 1
        // masked neighbor: drive exp2 args to -inf -> weight exactly 0.
        // x2 must be 0 (not INF): its coeff (ea-eb) can be positive -> NaN risk;
        // xy2=INF (negative coeff) already forces the ellip arg to -inf.
        x2[j]  = act ? a : 0.0f;
        z2[j]  = act ? c : INF;
        xy2[j] = act ? (a+b) : INF;
        rxy[j] = act ? __builtin_amdgcn_sqrtf(a+b+EPS) : INF;
        zz[j]  = rz;
    }

    float o0 = 0.f, o1 = 0.f;
    const float2* lamp = (const float2*)s_lam + sub;   // row stride = 8 float2

    #pragma unroll
    for (int g = 0; g < G; g++) {
        const float4 pA = *(const float4*)(s_par + g*8);     // ccy,inc,ccn,da
        const float4 pB = *(const float4*)(s_par + g*8 + 4); // db,exy,exx,ezz
        float a0=0.f, a1=0.f, a2=0.f, a3=0.f;
        #pragma unroll
        for (int j = 0; j < KP; j++) {
            // cylinder
            a0 += __builtin_amdgcn_exp2f(xy2[j] * pA.x);
            // cone
            float d = __builtin_fmaf(-pA.y, zz[j], rxy[j]);
            a1 += __builtin_amdgcn_exp2f(d*d * pA.z);
            // disk
            a2 += __builtin_amdgcn_exp2f(__builtin_fmaf(xy2[j], pA.w, z2[j]*pB.x));
            // ellipsoid
            a3 += __builtin_amdgcn_exp2f(__builtin_fmaf(xy2[j], pB.y,
                          __builtin_fmaf(x2[j], pB.z, z2[j]*pB.w)));
        }
        // allreduce the 4 kind-partials across the 8 lanes of this query
        a0 += __shfl_xor(a0,1); a0 += __shfl_xor(a0,2); a0 += __shfl_xor(a0,4);
        a1 += __shfl_xor(a1,1); a1 += __shfl_xor(a1,2); a1 += __shfl_xor(a1,4);
        a2 += __shfl_xor(a2,1); a2 += __shfl_xor(a2,2); a2 += __shfl_xor(a2,4);
        a3 += __shfl_xor(a3,1); a3 += __shfl_xor(a3,2); a3 += __shfl_xor(a3,4);
        // fold lambda for this thread's 2 output columns immediately
        float2 l;
        l = lamp[(      g)*8]; o0 = __builtin_fmaf(a0,l.x,o0); o1 = __builtin_fmaf(a0,l.y,o1);
        l = lamp[(G   + g)*8]; o0 = __builtin_fmaf(a1,l.x,o0); o1 = __builtin_fmaf(a1,l.y,o1);
        l = lamp[(2*G + g)*8]; o0 = __builtin_fmaf(a2,l.x,o0); o1 = __builtin_fmaf(a2,l.y,o1);
        l = lamp[(3*G + g)*8]; o0 = __builtin_fmaf(a3,l.x,o0); o1 = __builtin_fmaf(a3,l.y,o1);
    }

    const float s = 1.0f / (float)KNBR;
    *(float2*)(out + (size_t)m * OBS + sub*2) = make_float2(o0*s, o1*s);
}

extern "C" void kernel_launch(void* const* d_in, const int* in_sizes, int n_in,
                              void* d_out, int out_size, void* d_ws, size_t ws_size,
                              hipStream_t stream) {
    const float* points      = (const float*)d_in[0];
    const float* q_coords    = (const float*)d_in[1];
    const int*   sidx        = (const int*)  d_in[2];
    const float* cy_radius   = (const float*)d_in[3];
    const float* disk_radius = (const float*)d_in[4];
    const float* disk_width  = (const float*)d_in[5];
    const float* cone_radius = (const float*)d_in[6];
    const float* cone_inc    = (const float*)d_in[7];
    const float* ellip_radii = (const float*)d_in[8];
    const float* lambdas     = (const float*)d_in[9];
    float* out = (float*)d_out;

    const int N = in_sizes[0] / 3;
    const int M = in_sizes[1] / 3;
    const int grid = (M * TPQ + BLOCK - 1) / BLOCK;
    gib_kernel<<<grid, BLOCK, 0, stream>>>(points, q_coords, sidx,
                                           cy_radius, disk_radius, disk_width,
                                           cone_radius, cone_inc, ellip_radii,
                                           lambdas, out, M, N);
}

// Round 4
// 16.277 us; speedup vs baseline: 1.6684x; 1.3010x over previous
//
#include <hip/hip_runtime.h>

#define KNBR 32
#define G 8
#define OBS 16
#define KP 4          // neighbors per thread
#define TPQ 8         // threads (lanes) per query
#define BLOCK 256

// float4 with relaxed alignment: one global_load_dwordx4 at a 4B-aligned
// address covers the 12B float3 (single gather instr per point).
typedef float f4u __attribute__((ext_vector_type(4), aligned(4)));

__global__ __launch_bounds__(BLOCK, 6) void gib_kernel(
    const float* __restrict__ points,
    const float* __restrict__ q_coords,
    const int*   __restrict__ sidx,
    const float* __restrict__ cy_radius,
    const float* __restrict__ disk_radius,
    const float* __restrict__ disk_width,
    const float* __restrict__ cone_radius,
    const float* __restrict__ cone_inc,
    const float* __restrict__ ellip_radii,
    const float* __restrict__ lambdas,
    float* __restrict__ out,
    int M, int N)
{
    // per-g params: [g][0..7] = ccy, inc, ccn, da, db, e_xy, e_xx, e_zz
    __shared__ __align__(16) float s_par[G * 8];
    // transposed lambda: [col][j], row padded to 36 floats (bank rotation)
    __shared__ __align__(16) float s_lamT[OBS][36];
    // neighbor features, j-major: [j][thread] = {xy2, x2, z2, z}
    __shared__ float4 s_feat[KP][BLOCK];
    // per query-group accumulators: 32 j-rows (kind*8+g), padded stride 36
    __shared__ __align__(16) float s_acc[32][36];

    const float NL2E = -0.5f * 1.44269504088896340736f;
    const float EPS  = 1e-8f;

    const int t = threadIdx.x;
    if (t < G) {
        float r;
        r = cy_radius[t];        s_par[t*8 + 0] = NL2E / (r*r + EPS);
        s_par[t*8 + 1] = cone_inc[t];
        r = cone_radius[t];      s_par[t*8 + 2] = NL2E / (r*r + EPS);
        r = disk_radius[t];      s_par[t*8 + 3] = NL2E / (r*r + EPS);
        r = disk_width[t];       s_par[t*8 + 4] = NL2E / (r*r + EPS);
        float ra = ellip_radii[3*t+0];
        float rb = ellip_radii[3*t+1];
        float rc = ellip_radii[3*t+2];
        float ea = NL2E / (ra*ra + EPS);
        float eb = NL2E / (rb*rb + EPS);
        float ec = NL2E / (rc*rc + EPS);
        // x2*ea + y2*eb + z2*ec == xy2*eb + x2*(ea-eb) + z2*ec
        s_par[t*8 + 5] = eb;        // coeff of xy2
        s_par[t*8 + 6] = ea - eb;   // coeff of x2
        s_par[t*8 + 7] = ec;        // coeff of z2
    }
    // stage lambda transposed: lamT[c][j] = lambdas[j*16+c]
    {
        int e0 = t, e1 = t + 256;
        s_lamT[e0 & 15][e0 >> 4] = lambdas[e0];
        s_lamT[e1 & 15][e1 >> 4] = lambdas[e1];
    }
    __syncthreads();

    const int gid = blockIdx.x * BLOCK + t;
    const int m   = gid >> 3;       // query index
    const int sub = t & 7;          // lane within query group
    if (m >= M) return;

    // neighbor indices: one int4 (8 lanes cover 128B contiguous per query)
    const int4 iv = *(const int4*)(sidx + (size_t)m * KNBR + sub * KP);
    const int id[KP] = {iv.x, iv.y, iv.z, iv.w};

    const float qx = q_coords[3*m + 0];
    const float qy = q_coords[3*m + 1];
    const float qz = q_coords[3*m + 2];

    // gather: ONE dwordx4 per point, clamped window (never reads past end)
    const int maxoff = 3 * N - 4;
    float px[KP], py[KP], pz[KP];
    #pragma unroll
    for (int j = 0; j < KP; j++) {
        int off  = 3 * id[j];
        int offc = off > maxoff ? maxoff : off;
        f4u p = *(const f4u*)(points + offc);
        bool sh = (off != offc);
        px[j] = sh ? p.y : p.x;
        py[j] = sh ? p.z : p.y;
        pz[j] = sh ? p.w : p.z;
    }

    // features + 4-bit active mask
    unsigned am = 0;
    #pragma unroll
    for (int j = 0; j < KP; j++) {
        float rx = px[j]-qx, ry = py[j]-qy, rz = pz[j]-qz;
        float a = rx*rx, b = ry*ry, c = rz*rz;
        if (a + b + c <= 1.0f) am |= (1u << j);      // REACH^2 = 1
        s_feat[j][t] = make_float4(a + b, a, c, rz); // xy2, x2, z2, z
    }
    // merge to full 32-bit per-query active mask (slot = owner_sub*4 + j)
    am <<= (sub * 4);
    am |= __shfl_xor((int)am, 1);
    am |= __shfl_xor((int)am, 2);
    am |= __shfl_xor((int)am, 4);

    // this lane's g params
    const float4 pA = *(const float4*)(s_par + sub*8);     // ccy,inc,ccn,da
    const float4 pB = *(const float4*)(s_par + sub*8 + 4); // db,exy,exx,ezz

    // features visible to the other lanes of this wave
    asm volatile("s_waitcnt lgkmcnt(0)" ::: "memory");

    // walk ACTIVE neighbors only (~8% of 32), uniform within the 8-lane group
    float s0 = 0.f, s1 = 0.f, s2 = 0.f, s3 = 0.f;
    const int gbase = t & ~7;
    while (am) {
        const int slot = __builtin_ctz(am);
        am &= am - 1;
        float4 f = s_feat[slot & 3][gbase + (slot >> 2)];
        float xy2 = f.x, x2 = f.y, z2 = f.z, zz = f.w;
        float rxy = __builtin_amdgcn_sqrtf(xy2 + EPS);
        // cylinder
        s0 += __builtin_amdgcn_exp2f(xy2 * pA.x);
        // cone
        float d = __builtin_fmaf(-pA.y, zz, rxy);
        s1 += __builtin_amdgcn_exp2f(d * d * pA.z);
        // disk
        s2 += __builtin_amdgcn_exp2f(__builtin_fmaf(xy2, pA.w, z2 * pB.x));
        // ellipsoid
        s3 += __builtin_amdgcn_exp2f(__builtin_fmaf(xy2, pB.y,
                     __builtin_fmaf(x2, pB.z, z2 * pB.w)));
    }

    // scatter this lane's (kind, g=sub) sums into the group's 32-row acc
    const int gq = t >> 3;
    float* arow = &s_acc[gq][sub];
    arow[0]  = s0;      // cy    row  0+sub
    arow[8]  = s1;      // cone  row  8+sub
    arow[16] = s2;      // disk  row 16+sub
    arow[24] = s3;      // ellip row 24+sub
    asm volatile("s_waitcnt lgkmcnt(0)" ::: "memory");

    // fold: o[c] = sum_j acc[j] * lamT[c][j]  for this lane's 2 columns
    const float4* av = (const float4*)s_acc[gq];
    const float4* l0 = (const float4*)s_lamT[2*sub];
    const float4* l1 = (const float4*)s_lamT[2*sub + 1];
    float o0 = 0.f, o1 = 0.f;
    #pragma unroll
    for (int r = 0; r < 8; r++) {
        float4 a4 = av[r], b0 = l0[r], b1 = l1[r];
        o0 = __builtin_fmaf(a4.x, b0.x, o0);
        o0 = __builtin_fmaf(a4.y, b0.y, o0);
        o0 = __builtin_fmaf(a4.z, b0.z, o0);
        o0 = __builtin_fmaf(a4.w, b0.w, o0);
        o1 = __builtin_fmaf(a4.x, b1.x, o1);
        o1 = __builtin_fmaf(a4.y, b1.y, o1);
        o1 = __builtin_fmaf(a4.z, b1.z, o1);
        o1 = __builtin_fmaf(a4.w, b1.w, o1);
    }

    const float s = 1.0f / (float)KNBR;
    *(float2*)(out + (size_t)m * OBS + sub*2) = make_float2(o0*s, o1*s);
}

extern "C" void kernel_launch(void* const* d_in, const int* in_sizes, int n_in,
                              void* d_out, int out_size, void* d_ws, size_t ws_size,
                              hipStream_t stream) {
    const float* points      = (const float*)d_in[0];
    const float* q_coords    = (const float*)d_in[1];
    const int*   sidx        = (const int*)  d_in[2];
    const float* cy_radius   = (const float*)d_in[3];
    const float* disk_radius = (const float*)d_in[4];
    const float* disk_width  = (const float*)d_in[5];
    const float* cone_radius = (const float*)d_in[6];
    const float* cone_inc    = (const float*)d_in[7];
    const float* ellip_radii = (const float*)d_in[8];
    const float* lambdas     = (const float*)d_in[9];
    float* out = (float*)d_out;

    const int N = in_sizes[0] / 3;
    const int M = in_sizes[1] / 3;
    const int grid = (M * TPQ + BLOCK - 1) / BLOCK;
    gib_kernel<<<grid, BLOCK, 0, stream>>>(points, q_coords, sidx,
                                           cy_radius, disk_radius, disk_width,
                                           cone_radius, cone_inc, ellip_radii,
                                           lambdas, out, M, N);
}

// Round 5
// 16.001 us; speedup vs baseline: 1.6971x; 1.0172x over previous
//
#include <hip/hip_runtime.h>

#define KNBR 32
#define G 8
#define OBS 16
#define KP 2          // neighbors per thread
#define TPQ 16        // threads (lanes) per query
#define BLOCK 256

// float4 with relaxed alignment: one global_load_dwordx4 at a 4B-aligned
// address covers the 12B float3 (single gather instr per point).
typedef float f4u __attribute__((ext_vector_type(4), aligned(4)));

__global__ __launch_bounds__(BLOCK, 8) void gib_kernel(
    const float* __restrict__ points,
    const float* __restrict__ q_coords,
    const int*   __restrict__ sidx,
    const float* __restrict__ cy_radius,
    const float* __restrict__ disk_radius,
    const float* __restrict__ disk_width,
    const float* __restrict__ cone_radius,
    const float* __restrict__ cone_inc,
    const float* __restrict__ ellip_radii,
    const float* __restrict__ lambdas,
    float* __restrict__ out,
    int M, int N)
{
    // per-lane coefficient table: [lane16][A,B,Rc,P,C,D,E,F]
    // lane = khalf*8 + g. khalf0 -> (cy, cone), khalf1 -> (disk, ellip)
    //   q0 = xy2*A + z2*B            (cy: A=ccy,B=0 | disk: A=da,B=db)
    //   d  = Rc*rxy + P*z            (cone: Rc=1,P=-inc | else 0)
    //   q1 = d*d*C + xy2*D + x2*E + z2*F
    //        (cone: C=ccn,D=E=F=0 | ellip: C=0,D=exy,E=exx,F=ezz)
    __shared__ __align__(16) float s_kpar[16][8];
    // transposed lambda: [col][j], row padded to 36 floats
    __shared__ __align__(16) float s_lamT[OBS][36];
    // neighbor features, j-major: [j][thread] = {xy2, x2, z2, z} (active only)
    __shared__ float4 s_feat[KP][BLOCK];
    // per query-group accumulators: 32 rows (kind*8+g), padded stride 36
    __shared__ __align__(16) float s_acc[BLOCK / TPQ][36];

    const float NL2E = -0.5f * 1.44269504088896340736f;
    const float EPS  = 1e-8f;

    const int t = threadIdx.x;
    if (t < 16) {
        const int g = t & 7;
        float* kp = s_kpar[t];
        if (t < 8) {            // cy + cone
            float r  = cy_radius[g];
            float rc = cone_radius[g];
            kp[0] = NL2E / (r * r + EPS);   // A = ccy
            kp[1] = 0.0f;                   // B
            kp[2] = 1.0f;                   // Rc
            kp[3] = -cone_inc[g];           // P
            kp[4] = NL2E / (rc * rc + EPS); // C = ccn
            kp[5] = 0.0f; kp[6] = 0.0f; kp[7] = 0.0f;
        } else {                // disk + ellip
            float rd = disk_radius[g];
            float rw = disk_width[g];
            float ra = ellip_radii[3*g+0];
            float rb = ellip_radii[3*g+1];
            float rcc = ellip_radii[3*g+2];
            float ea = NL2E / (ra * ra + EPS);
            float eb = NL2E / (rb * rb + EPS);
            float ec = NL2E / (rcc * rcc + EPS);
            kp[0] = NL2E / (rd * rd + EPS); // A = da
            kp[1] = NL2E / (rw * rw + EPS); // B = db
            kp[2] = 0.0f;                   // Rc
            kp[3] = 0.0f;                   // P
            kp[4] = 0.0f;                   // C
            kp[5] = eb;                     // D = coeff(xy2)
            kp[6] = ea - eb;                // E = coeff(x2)
            kp[7] = ec;                     // F = coeff(z2)
        }
    }
    // stage lambda transposed: lamT[c][j] = lambdas[j*16+c]
    {
        int e0 = t, e1 = t + 256;
        s_lamT[e0 & 15][e0 >> 4] = lambdas[e0];
        s_lamT[e1 & 15][e1 >> 4] = lambdas[e1];
    }
    __syncthreads();

    const int gid = blockIdx.x * BLOCK + t;
    const int m   = gid >> 4;       // query index
    const int sub = t & 15;         // lane within query group
    if (m >= M) return;

    // 2 neighbor indices: one int2 (16 lanes cover 128B contiguous per query)
    const int2 iv = *(const int2*)(sidx + (size_t)m * KNBR + sub * KP);
    const int id[KP] = {iv.x, iv.y};

    const float qx = q_coords[3*m + 0];
    const float qy = q_coords[3*m + 1];
    const float qz = q_coords[3*m + 2];

    // gather: ONE dwordx4 per point, clamped window (never reads past end)
    const int maxoff = 3 * N - 4;
    float px[KP], py[KP], pz[KP];
    #pragma unroll
    for (int j = 0; j < KP; j++) {
        int off  = 3 * id[j];
        int offc = off > maxoff ? maxoff : off;
        f4u p = *(const f4u*)(points + offc);
        bool sh = (off != offc);
        px[j] = sh ? p.y : p.x;
        py[j] = sh ? p.z : p.y;
        pz[j] = sh ? p.w : p.z;
    }

    // features (written only for ACTIVE neighbors) + 2-bit active mask
    unsigned am = 0;
    #pragma unroll
    for (int j = 0; j < KP; j++) {
        float rx = px[j]-qx, ry = py[j]-qy, rz = pz[j]-qz;
        float a = rx*rx, b = ry*ry, c = rz*rz;
        if (a + b + c <= 1.0f) {             // REACH^2 = 1
            am |= (1u << j);
            s_feat[j][t] = make_float4(a + b, a, c, rz); // xy2, x2, z2, z
        }
    }
    // merge to full 32-bit per-query mask (slot = owner_sub*2 + j)
    am <<= (sub * 2);
    am |= __shfl_xor((int)am, 1);
    am |= __shfl_xor((int)am, 2);
    am |= __shfl_xor((int)am, 4);
    am |= __shfl_xor((int)am, 8);

    // this lane's coefficients
    const float4 cA = *(const float4*)(s_kpar[sub]);     // A,B,Rc,P
    const float4 cB = *(const float4*)(s_kpar[sub] + 4); // C,D,E,F

    // features visible to the other lanes of this wave
    asm volatile("s_waitcnt lgkmcnt(0)" ::: "memory");

    // walk ACTIVE neighbors only (~8% of 32), uniform within the 16-lane group
    float s0 = 0.f, s1 = 0.f;
    const int gbase = t & ~15;
    while (am) {
        const int slot = __builtin_ctz(am);
        am &= am - 1;
        float4 f = s_feat[slot & 1][gbase + (slot >> 1)];
        const float xy2 = f.x, x2 = f.y, z2 = f.z, zz = f.w;
        const float rxy = __builtin_amdgcn_sqrtf(xy2 + EPS);
        // q0: cy / disk
        float q0 = __builtin_fmaf(xy2, cA.x, z2 * cA.y);
        // q1: cone / ellip (branch-free: Rc,P,C or D,E,F are zero per half)
        float d  = __builtin_fmaf(cA.z, rxy, cA.w * zz);
        float q1 = __builtin_fmaf(d * d, cB.x,
                     __builtin_fmaf(xy2, cB.y,
                       __builtin_fmaf(x2, cB.z, z2 * cB.w)));
        s0 += __builtin_amdgcn_exp2f(q0);
        s1 += __builtin_amdgcn_exp2f(q1);
    }

    // scatter the two (kind, g) sums into the group's 32-row acc
    const int gq = t >> 4;
    float* arow = &s_acc[gq][(sub & 7) | ((sub & 8) << 1)];
    arow[0] = s0;       // kind 2*khalf     (cy / disk)
    arow[8] = s1;       // kind 2*khalf + 1 (cone / ellip)
    asm volatile("s_waitcnt lgkmcnt(0)" ::: "memory");

    // fold: o = sum_j acc[j] * lamT[sub][j]  (this lane's single column)
    const float4* av = (const float4*)s_acc[gq];
    const float4* lv = (const float4*)s_lamT[sub];
    float o = 0.f;
    #pragma unroll
    for (int r = 0; r < 8; r++) {
        float4 a4 = av[r], b4 = lv[r];
        o = __builtin_fmaf(a4.x, b4.x, o);
        o = __builtin_fmaf(a4.y, b4.y, o);
        o = __builtin_fmaf(a4.z, b4.z, o);
        o = __builtin_fmaf(a4.w, b4.w, o);
    }

    out[(size_t)m * OBS + sub] = o * (1.0f / (float)KNBR);
}

extern "C" void kernel_launch(void* const* d_in, const int* in_sizes, int n_in,
                              void* d_out, int out_size, void* d_ws, size_t ws_size,
                              hipStream_t stream) {
    const float* points      = (const float*)d_in[0];
    const float* q_coords    = (const float*)d_in[1];
    const int*   sidx        = (const int*)  d_in[2];
    const float* cy_radius   = (const float*)d_in[3];
    const float* disk_radius = (const float*)d_in[4];
    const float* disk_width  = (const float*)d_in[5];
    const float* cone_radius = (const float*)d_in[6];
    const float* cone_inc    = (const float*)d_in[7];
    const float* ellip_radii = (const float*)d_in[8];
    const float* lambdas     = (const float*)d_in[9];
    float* out = (float*)d_out;

    const int N = in_sizes[0] / 3;
    const int M = in_sizes[1] / 3;
    const int grid = (M * TPQ + BLOCK - 1) / BLOCK;
    gib_kernel<<<grid, BLOCK, 0, stream>>>(points, q_coords, sidx,
                                           cy_radius, disk_radius, disk_width,
                                           cone_radius, cone_inc, ellip_radii,
                                           lambdas, out, M, N);
}